// Round 4
// baseline (421.447 us; speedup 1.0000x reference)
//
#include <hip/hip_runtime.h>

#define MAXLEN 100
#define HDIM 64
#define HSTR 72   // ushorts per h row (144 B, 16B-aligned)

typedef __attribute__((ext_vector_type(8))) short bf16x8;
typedef __attribute__((ext_vector_type(4))) float f32x4;

__device__ __forceinline__ unsigned short f2bf_u(float f) {   // RNE f32->bf16
    unsigned u = __float_as_uint(f);
    u += 0x7fffu + ((u >> 16) & 1u);
    return (unsigned short)(u >> 16);
}
__device__ __forceinline__ unsigned pk2(float a, float b) {
    return (unsigned)f2bf_u(a) | ((unsigned)f2bf_u(b) << 16);
}
__device__ __forceinline__ bf16x8 pack8(f32x4 a, f32x4 b) {
    union { unsigned u[4]; bf16x8 v; } c;
    c.u[0] = pk2(a[0], a[1]); c.u[1] = pk2(a[2], a[3]);
    c.u[2] = pk2(b[0], b[1]); c.u[3] = pk2(b[2], b[3]);
    return c.v;
}
__device__ __forceinline__ float fsig(float v) {
    return __fdividef(1.0f, 1.0f + __expf(-v));
}
__device__ __forceinline__ float ftanh(float v) {
    return __fdividef(2.0f, 1.0f + __expf(-2.0f * v)) - 1.0f;
}

// --- per-segment start/len via binary search (index sorted) ---
__global__ void seg_bounds_kernel(const int* __restrict__ index, int N, int B,
                                  int* __restrict__ starts, int* __restrict__ lens) {
    int b = blockIdx.x * blockDim.x + threadIdx.x;
    if (b >= B) return;
    int lo = 0, hi = N;
    while (lo < hi) { int mid = (lo + hi) >> 1; if (index[mid] < b) lo = mid + 1; else hi = mid; }
    int s = lo;
    hi = N;
    while (lo < hi) { int mid = (lo + hi) >> 1; if (index[mid] < b + 1) lo = mid + 1; else hi = mid; }
    int len = lo - s;
    starts[b] = s;
    lens[b] = len < MAXLEN ? len : MAXLEN;
}

// --- Single-wave recurrent kernel: 8 segments per 64-thread block, no barriers.
// A-rows duplicated (row=l15 -> seg=l15>>1) so C rows 4q and 4q+2 spread every
// (seg,hidden) gate bundle across all 64 lanes: 8 bundles/lane, zero shuffles.
// h crosses only wave-private LDS (lgkmcnt, no s_barrier) -> x prefetch overlaps.
__global__ __launch_bounds__(64, 1)
void lstm_wave_kernel(const float* __restrict__ x,
                      const float* __restrict__ Wih,
                      const float* __restrict__ Whh,
                      const float* __restrict__ bih,
                      const float* __restrict__ bhh,
                      const int* __restrict__ starts,
                      const int* __restrict__ lens,
                      float* __restrict__ out, int B) {
    const int lane = threadIdx.x;          // 0..63 (one wave)
    const int l15  = lane & 15;
    const int quad = lane >> 4;
    const int segbase = blockIdx.x * 8;

    __shared__ __align__(16) unsigned short hst[2][8][HSTR];

    // Weight B-fragments: 16 N-tiles (4 gates x 4 hidden-quarters) x 2 K-tiles.
    // B[k][n]: n = l15 -> W row gcol; k = kt*32 + quad*8 + j.
    bf16x8 wi[4][4][2], wh[4][4][2];
    float bsc[4][4];                        // bias for (gate, nh) at col l15
#pragma unroll
    for (int g = 0; g < 4; ++g) {
#pragma unroll
        for (int nh = 0; nh < 4; ++nh) {
            const int gcol = g * HDIM + nh * 16 + l15;
            bsc[g][nh] = bih[gcol] + bhh[gcol];
#pragma unroll
            for (int kt = 0; kt < 2; ++kt) {
                const f32x4* pi = (const f32x4*)(Wih + (size_t)gcol * HDIM + kt * 32 + quad * 8);
                const f32x4* ph = (const f32x4*)(Whh + (size_t)gcol * HDIM + kt * 32 + quad * 8);
                wi[g][nh][kt] = pack8(pi[0], pi[1]);
                wh[g][nh][kt] = pack8(ph[0], ph[1]);
            }
        }
    }

    // Segment metadata. A-row segment for this lane (duplicated pairs):
    const int rowseg = segbase + (l15 >> 1);
    const int rs     = rowseg < B ? rowseg : B - 1;
    const int startA = starts[rs];
    const int lenRow = (rowseg < B) ? lens[rs] : 0;
    // Gate-math home segments: seg 2q (C reg r=0) and 2q+1 (r=2).
    const int sA = segbase + 2 * quad;
    const int sB = segbase + 2 * quad + 1;
    const int lenA = (sA < B) ? lens[sA] : 0;
    const int lenB = (sB < B) ? lens[sB] : 0;

    int lmax = lenRow;
#pragma unroll
    for (int d = 1; d < 64; d <<= 1) {
        int o = __shfl_xor(lmax, d);
        lmax = o > lmax ? o : lmax;
    }

    // Zero h stage (wave-private; no barrier needed beyond lgkm deps).
    for (int i = lane; i < 2 * 8 * HSTR / 2; i += 64) ((int*)hst)[i] = 0;
    __syncthreads();   // single wave: compiles to a cheap waitcnt

    const float* xrow = x + (size_t)startA * HDIM + quad * 8;

    bf16x8 xa0 = {0,0,0,0,0,0,0,0}, xa1 = xa0;
    if (lenRow > 0) {
        const f32x4* p0 = (const f32x4*)(xrow);
        const f32x4* p1 = (const f32x4*)(xrow + 32);
        xa0 = pack8(p0[0], p0[1]);
        xa1 = pack8(p1[0], p1[1]);
    }
    f32x4 nx0, nx1, nx2, nx3;

    float cA[4] = {0,0,0,0}, hA[4] = {0,0,0,0};
    float cB[4] = {0,0,0,0}, hB[4] = {0,0,0,0};
    const f32x4 cz = {0.0f, 0.0f, 0.0f, 0.0f};

    for (int t = 0; t < lmax; ++t) {
        // Prefetch x(t+1) as fp32 (converted after the MFMAs).
        const bool pf = (t + 1 < lenRow);
        if (pf) {
            const f32x4* p = (const f32x4*)(xrow + (size_t)(t + 1) * HDIM);
            nx0 = p[0]; nx1 = p[1];
            const f32x4* q = (const f32x4*)(xrow + (size_t)(t + 1) * HDIM + 32);
            nx2 = q[0]; nx3 = q[1];
        }

        // h A-fragments (rows duplicated: row l15 -> seg l15>>1). LDS broadcast.
        const unsigned short* hr = &hst[t & 1][l15 >> 1][quad * 8];
        bf16x8 ha0 = *(const bf16x8*)(hr);
        bf16x8 ha1 = *(const bf16x8*)(hr + 32);

        // 64 MFMAs: 16 tiles x (2 x-K + 2 h-K).
        f32x4 acc[4][4];
#pragma unroll
        for (int g = 0; g < 4; ++g) {
#pragma unroll
            for (int nh = 0; nh < 4; ++nh) {
                f32x4 a = __builtin_amdgcn_mfma_f32_16x16x32_bf16(xa0, wi[g][nh][0], cz, 0, 0, 0);
                a = __builtin_amdgcn_mfma_f32_16x16x32_bf16(xa1, wi[g][nh][1], a, 0, 0, 0);
                a = __builtin_amdgcn_mfma_f32_16x16x32_bf16(ha0, wh[g][nh][0], a, 0, 0, 0);
                a = __builtin_amdgcn_mfma_f32_16x16x32_bf16(ha1, wh[g][nh][1], a, 0, 0, 0);
                acc[g][nh] = a;
            }
        }

        // Gate math: 8 bundles/lane (2 segs x 4 hidden-quarters), register-local.
        unsigned short* hwA = &hst[(t + 1) & 1][2 * quad][l15];
        unsigned short* hwB = &hst[(t + 1) & 1][2 * quad + 1][l15];
#pragma unroll
        for (int nh = 0; nh < 4; ++nh) {
            {   // seg 2q  (C row 4q   -> reg 0)
                float gi = fsig (acc[0][nh][0] + bsc[0][nh]);
                float gf = fsig (acc[1][nh][0] + bsc[1][nh]);
                float gg = ftanh(acc[2][nh][0] + bsc[2][nh]);
                float go = fsig (acc[3][nh][0] + bsc[3][nh]);
                float cn = gf * cA[nh] + gi * gg;
                float hn = go * ftanh(cn);
                if (t < lenA) { cA[nh] = cn; hA[nh] = hn; }
                hwA[nh * 16] = f2bf_u(hA[nh]);
            }
            {   // seg 2q+1 (C row 4q+2 -> reg 2)
                float gi = fsig (acc[0][nh][2] + bsc[0][nh]);
                float gf = fsig (acc[1][nh][2] + bsc[1][nh]);
                float gg = ftanh(acc[2][nh][2] + bsc[2][nh]);
                float go = fsig (acc[3][nh][2] + bsc[3][nh]);
                float cn = gf * cB[nh] + gi * gg;
                float hn = go * ftanh(cn);
                if (t < lenB) { cB[nh] = cn; hB[nh] = hn; }
                hwB[nh * 16] = f2bf_u(hB[nh]);
            }
        }

        if (pf) { xa0 = pack8(nx0, nx1); xa1 = pack8(nx2, nx3); }
    }

#pragma unroll
    for (int nh = 0; nh < 4; ++nh) {
        const int hid = nh * 16 + l15;
        if (sA < B) out[(size_t)sA * HDIM + hid] = hA[nh];
        if (sB < B) out[(size_t)sB * HDIM + hid] = hB[nh];
    }
}

extern "C" void kernel_launch(void* const* d_in, const int* in_sizes, int n_in,
                              void* d_out, int out_size, void* d_ws, size_t ws_size,
                              hipStream_t stream) {
    const float* x     = (const float*)d_in[0];
    const float* Wih   = (const float*)d_in[1];
    const float* Whh   = (const float*)d_in[2];
    const float* bih   = (const float*)d_in[3];
    const float* bhh   = (const float*)d_in[4];
    const int*   index = (const int*)d_in[5];

    const int N = in_sizes[5];
    const int B = out_size / HDIM;   // 8192

    int* starts = (int*)d_ws;
    int* lens   = starts + B;

    seg_bounds_kernel<<<(B + 255) / 256, 256, 0, stream>>>(index, N, B, starts, lens);

    const int nblocks = (B + 7) / 8;   // 1024: one wave per SIMD chip-wide
    lstm_wave_kernel<<<nblocks, 64, 0, stream>>>(x, Wih, Whh, bih, bhh,
                                                 starts, lens, (float*)d_out, B);
}

// Round 5
// 304.957 us; speedup vs baseline: 1.3820x; 1.3820x over previous
//
#include <hip/hip_runtime.h>

#define MAXLEN 100
#define HDIM 64
#define CH 16                    // x-staging chunk length (steps)
#define SROW 72                  // ushorts per x step-row (144 B; bank offset 4 dw/step)
#define SPLANE (16 * SROW + 8)   // 1160 ushorts per segment plane (bank offset 4 dw/seg)
#define HSTR 72                  // ushorts per h row (144 B)

typedef __attribute__((ext_vector_type(8))) short bf16x8;
typedef __attribute__((ext_vector_type(4))) float f32x4;

__device__ __forceinline__ unsigned short f2bf_u(float f) {   // RNE f32->bf16
    unsigned u = __float_as_uint(f);
    u += 0x7fffu + ((u >> 16) & 1u);
    return (unsigned short)(u >> 16);
}
__device__ __forceinline__ unsigned pk2(float a, float b) {
    return (unsigned)f2bf_u(a) | ((unsigned)f2bf_u(b) << 16);
}
__device__ __forceinline__ bf16x8 pack8(f32x4 a, f32x4 b) {
    union { unsigned u[4]; bf16x8 v; } c;
    c.u[0] = pk2(a[0], a[1]); c.u[1] = pk2(a[2], a[3]);
    c.u[2] = pk2(b[0], b[1]); c.u[3] = pk2(b[2], b[3]);
    return c.v;
}
__device__ __forceinline__ float fsig(float v) {
    return __fdividef(1.0f, 1.0f + __expf(-v));
}
__device__ __forceinline__ float ftanh(float v) {
    return __fdividef(2.0f, 1.0f + __expf(-2.0f * v)) - 1.0f;
}

// Single fused kernel: 512 blocks x 256 threads; 16 segments/block; 4 waves,
// wave w owns hidden cols [16w,16w+16) for all 4 gates (R3-verified mapping).
// x is staged into LDS in 16-step chunks (bf16), with global loads for chunk
// n+1 issued a full chunk early -> per-step barriers never wait on HBM.
__global__ __launch_bounds__(256, 2)
void lstm_fused_kernel(const float* __restrict__ x,
                       const float* __restrict__ Wih,
                       const float* __restrict__ Whh,
                       const float* __restrict__ bih,
                       const float* __restrict__ bhh,
                       const int* __restrict__ index,
                       float* __restrict__ out, int N, int B) {
    const int tid  = threadIdx.x;
    const int w    = tid >> 6;
    const int lane = tid & 63;
    const int l15  = lane & 15;
    const int quad = lane >> 4;
    const int segbase = blockIdx.x * 16;
    const int ncol = w * 16 + l15;

    __shared__ __align__(16) unsigned short xst[16 * SPLANE];   // 37120 B
    __shared__ __align__(16) unsigned short hst[2][16][HSTR];   //  4608 B
    __shared__ int sstart[16], slen[16];

    // --- fused per-block segment bounds (index sorted) ---
    if (tid < 16) {
        const int b = segbase + tid;
        int lo = 0, hi = N;
        while (lo < hi) { int m = (lo + hi) >> 1; if (index[m] < b) lo = m + 1; else hi = m; }
        const int s = lo;
        hi = N;
        while (lo < hi) { int m = (lo + hi) >> 1; if (index[m] < b + 1) lo = m + 1; else hi = m; }
        int len = lo - s;
        sstart[tid] = s;
        slen[tid] = len < MAXLEN ? len : MAXLEN;
    }
    // Zero h stage while bounds resolve.
    for (int i = tid; i < 2 * 16 * HSTR / 2; i += 256) ((int*)hst)[i] = 0;
    __syncthreads();

    // --- weight B-fragments + bias (register-resident, R3 layout) ---
    bf16x8 wi[4][2], wh[4][2];
    f32x4 bias4[4];
#pragma unroll
    for (int g = 0; g < 4; ++g) {
        const int row = g * HDIM + ncol;
        float bb = bih[row] + bhh[row];
        f32x4 b4 = {bb, bb, bb, bb};
        bias4[g] = b4;
#pragma unroll
        for (int kt = 0; kt < 2; ++kt) {
            const f32x4* pi = (const f32x4*)(Wih + (size_t)row * HDIM + kt * 32 + quad * 8);
            const f32x4* ph = (const f32x4*)(Whh + (size_t)row * HDIM + kt * 32 + quad * 8);
            wi[g][kt] = pack8(pi[0], pi[1]);
            wh[g][kt] = pack8(ph[0], ph[1]);
        }
    }

    // Per-lane metadata.
    int len4[4];
#pragma unroll
    for (int r = 0; r < 4; ++r) len4[r] = slen[quad * 4 + r];
    int lmax = 0;
#pragma unroll
    for (int i = 0; i < 16; ++i) { int v = slen[i]; lmax = v > lmax ? v : lmax; }

    // x-staging thread role: thread covers (seg sA, float cols jA*4..+3).
    const int sA = tid >> 4, jA = tid & 15;
    const int sbA = sstart[sA], slA = slen[sA];

    f32x4 pre[CH];   // one chunk of x data in flight (64 VGPRs)

    // issue: global loads for steps [t0, t0+CH) of segment sA (row-clamped).
#define ISSUE(t0_)                                                              \
    {                                                                           \
        _Pragma("unroll")                                                       \
        for (int t_ = 0; t_ < CH; ++t_) {                                       \
            int rr = (t0_) + t_;                                                \
            rr = (slA > 0) ? (rr < slA ? rr : slA - 1) : 0;                     \
            long long row = (long long)sbA + rr;                                \
            row = row < (long long)(N - 1) ? row : (long long)(N - 1);          \
            pre[t_] = *(const f32x4*)(x + row * HDIM + jA * 4);                 \
        }                                                                       \
    }
    // commit: pack chunk to bf16 and write into xst.
#define COMMIT()                                                                \
    {                                                                           \
        _Pragma("unroll")                                                       \
        for (int t_ = 0; t_ < CH; ++t_) {                                       \
            uint2 o;                                                            \
            o.x = pk2(pre[t_][0], pre[t_][1]);                                  \
            o.y = pk2(pre[t_][2], pre[t_][3]);                                  \
            *(uint2*)&xst[sA * SPLANE + t_ * SROW + jA * 4] = o;                \
        }                                                                       \
    }

    float c4[4] = {0, 0, 0, 0}, h4[4] = {0, 0, 0, 0};
    const int nch = (lmax + CH - 1) / CH;

    if (nch > 0) {
        ISSUE(0);
        COMMIT();
        __syncthreads();
        ISSUE(CH);   // chunk 1 in flight during chunk 0's steps

        for (int ch = 0; ch < nch; ++ch) {
            const int t0 = ch * CH;
#pragma unroll 2
            for (int tt = 0; tt < CH; ++tt) {
                const int t = t0 + tt;

                // x A-fragments straight from LDS (already bf16).
                const unsigned short* xr = &xst[l15 * SPLANE + tt * SROW + quad * 8];
                bf16x8 xa0 = *(const bf16x8*)(xr);
                bf16x8 xa1 = *(const bf16x8*)(xr + 32);
                // h A-fragments.
                const unsigned short* hr = &hst[t & 1][l15][quad * 8];
                bf16x8 ha0 = *(const bf16x8*)(hr);
                bf16x8 ha1 = *(const bf16x8*)(hr + 32);

                f32x4 acc[4];
#pragma unroll
                for (int g = 0; g < 4; ++g) {
                    f32x4 a = __builtin_amdgcn_mfma_f32_16x16x32_bf16(xa0, wi[g][0], bias4[g], 0, 0, 0);
                    a = __builtin_amdgcn_mfma_f32_16x16x32_bf16(xa1, wi[g][1], a, 0, 0, 0);
                    a = __builtin_amdgcn_mfma_f32_16x16x32_bf16(ha0, wh[g][0], a, 0, 0, 0);
                    a = __builtin_amdgcn_mfma_f32_16x16x32_bf16(ha1, wh[g][1], a, 0, 0, 0);
                    acc[g] = a;
                }

                unsigned short* hw = &hst[(t + 1) & 1][quad * 4][ncol];
#pragma unroll
                for (int r = 0; r < 4; ++r) {
                    float gi = fsig (acc[0][r]);
                    float gf = fsig (acc[1][r]);
                    float gg = ftanh(acc[2][r]);
                    float go = fsig (acc[3][r]);
                    float cn = gf * c4[r] + gi * gg;
                    float hn = go * ftanh(cn);
                    if (t < len4[r]) { c4[r] = cn; h4[r] = hn; }
                    hw[r * HSTR] = f2bf_u(h4[r]);
                }
                __syncthreads();
            }
            // Chunk boundary: stage chunk ch+1 (already landed), start chunk ch+2.
            if (ch + 1 < nch) {
                COMMIT();
                __syncthreads();
                ISSUE((ch + 2) * CH);
            }
        }
    }

#pragma unroll
    for (int r = 0; r < 4; ++r) {
        const int seg = segbase + quad * 4 + r;
        if (seg < B) out[(size_t)seg * HDIM + ncol] = h4[r];
    }
#undef ISSUE
#undef COMMIT
}

extern "C" void kernel_launch(void* const* d_in, const int* in_sizes, int n_in,
                              void* d_out, int out_size, void* d_ws, size_t ws_size,
                              hipStream_t stream) {
    const float* x     = (const float*)d_in[0];
    const float* Wih   = (const float*)d_in[1];
    const float* Whh   = (const float*)d_in[2];
    const float* bih   = (const float*)d_in[3];
    const float* bhh   = (const float*)d_in[4];
    const int*   index = (const int*)d_in[5];

    const int N = in_sizes[5];
    const int B = out_size / HDIM;   // 8192

    const int nblocks = (B + 15) / 16;   // 512
    lstm_fused_kernel<<<nblocks, 256, 0, stream>>>(x, Wih, Whh, bih, bhh, index,
                                                   (float*)d_out, N, B);
}

// Round 6
// 257.196 us; speedup vs baseline: 1.6386x; 1.1857x over previous
//
#include <hip/hip_runtime.h>

#define MAXLEN 100
#define HDIM 64
#define CH 8                       // x-staging chunk length (steps)
#define SROW 72                    // ushorts per x step-row (144 B)
#define SPLANE (CH * SROW + 8)     // 584 ushorts per segment plane
#define HSTR 72                    // ushorts per h row (144 B)
#define L2E 1.44269504f

typedef __attribute__((ext_vector_type(8))) short bf16x8;
typedef __attribute__((ext_vector_type(4))) float f32x4;

__device__ __forceinline__ unsigned short f2bf_u(float f) {   // RNE f32->bf16
    unsigned u = __float_as_uint(f);
    u += 0x7fffu + ((u >> 16) & 1u);
    return (unsigned short)(u >> 16);
}
__device__ __forceinline__ unsigned pk2(float a, float b) {
    return (unsigned)f2bf_u(a) | ((unsigned)f2bf_u(b) << 16);
}
__device__ __forceinline__ bf16x8 pack8(f32x4 a, f32x4 b) {
    union { unsigned u[4]; bf16x8 v; } c;
    c.u[0] = pk2(a[0], a[1]); c.u[1] = pk2(a[2], a[3]);
    c.u[2] = pk2(b[0], b[1]); c.u[3] = pk2(b[2], b[3]);
    return c.v;
}
// sigmoid(v + b) with bs = -L2E*b precomputed: rcp(1 + exp2(fma(v,-L2E,bs)))
__device__ __forceinline__ float sig_b(float v, float bs) {
    return __builtin_amdgcn_rcpf(1.0f + __builtin_amdgcn_exp2f(fmaf(v, -L2E, bs)));
}
// tanh(v + b) with bs2 = -2*L2E*b precomputed
__device__ __forceinline__ float tanh_b(float v, float bs2) {
    return fmaf(2.0f, __builtin_amdgcn_rcpf(1.0f + __builtin_amdgcn_exp2f(fmaf(v, -2.0f * L2E, bs2))), -1.0f);
}
__device__ __forceinline__ float tanh_p(float v) {
    return fmaf(2.0f, __builtin_amdgcn_rcpf(1.0f + __builtin_amdgcn_exp2f(v * (-2.0f * L2E))), -1.0f);
}

// Single fused kernel: 1024 blocks x 256 threads; 8 segments/block; 4 waves,
// wave w owns hidden cols [16w,16w+16) for all 4 gates.
// Segment s sits in MFMA A/C row ra = (s>>1)*4 + (s&1)  ({0,1,4,5,8,9,12,13}),
// so each lane's C regs 0..1 are its 2 real (seg,hid) bundles (segs 2*quad+r)
// -> per-lane gate transcendentals halved vs the 16-seg layout; C rows 2,3
// of each quad are garbage and never touched. Garbage A rows read zeros
// (x: dedicated zero plane 8; h: rows {2,3,6,7,...} zeroed once).
__global__ __launch_bounds__(256, 4)
void lstm8_kernel(const float* __restrict__ x,
                  const float* __restrict__ Wih,
                  const float* __restrict__ Whh,
                  const float* __restrict__ bih,
                  const float* __restrict__ bhh,
                  const int* __restrict__ index,
                  float* __restrict__ out, int N, int B) {
    const int tid  = threadIdx.x;
    const int w    = tid >> 6;
    const int lane = tid & 63;
    const int l15  = lane & 15;
    const int quad = lane >> 4;
    const int segbase = blockIdx.x * 8;
    const int ncol = w * 16 + l15;

    __shared__ __align__(16) unsigned short xst[9 * SPLANE];     // 10512 B (plane 8 = zeros)
    __shared__ __align__(16) unsigned short hst[2][16][HSTR];    //  4608 B
    __shared__ int sstart[8], slen[8];

    // --- per-block segment bounds (index sorted) ---
    if (tid < 8) {
        const int b = segbase + tid;
        int s = 0, len = 0;
        if (b < B) {
            int lo = 0, hi = N;
            while (lo < hi) { int m = (lo + hi) >> 1; if (index[m] < b) lo = m + 1; else hi = m; }
            s = lo;
            hi = N;
            while (lo < hi) { int m = (lo + hi) >> 1; if (index[m] < b + 1) lo = m + 1; else hi = m; }
            len = lo - s;
            len = len < MAXLEN ? len : MAXLEN;
        }
        sstart[tid] = s;
        slen[tid] = len;
    }
    // Zero h stage (both buffers) + x zero-plane.
    for (int i = tid; i < 2 * 16 * HSTR / 2; i += 256) ((int*)hst)[i] = 0;
    for (int i = tid; i < SPLANE / 2; i += 256) ((int*)xst)[8 * SPLANE / 2 + i] = 0;
    __syncthreads();

    // --- weight B-fragments (register-resident) + exp-folded biases ---
    bf16x8 wi[4][2], wh[4][2];
    float bs[4];   // gate g bias at col ncol, pre-scaled for the exp2 argument
#pragma unroll
    for (int g = 0; g < 4; ++g) {
        const int row = g * HDIM + ncol;
        const float bb = bih[row] + bhh[row];
        bs[g] = (g == 2) ? (-2.0f * L2E) * bb : (-L2E) * bb;
#pragma unroll
        for (int kt = 0; kt < 2; ++kt) {
            const f32x4* pi = (const f32x4*)(Wih + (size_t)row * HDIM + kt * 32 + quad * 8);
            const f32x4* ph = (const f32x4*)(Whh + (size_t)row * HDIM + kt * 32 + quad * 8);
            wi[g][kt] = pack8(pi[0], pi[1]);
            wh[g][kt] = pack8(ph[0], ph[1]);
        }
    }

    // Per-lane gate-math metadata: segs 2*quad+0 / 2*quad+1.
    int len2[2];
    len2[0] = slen[2 * quad];
    len2[1] = slen[2 * quad + 1];
    int lmax = 0;
#pragma unroll
    for (int i = 0; i < 8; ++i) { int v = slen[i]; lmax = v > lmax ? v : lmax; }

    // x-staging role: thread -> (seg sS, step sT within chunk, 16-float col group sC).
    const int sS = tid >> 5, sT = (tid >> 2) & 7, sC = tid & 3;
    const int sst = sstart[sS], sln = slen[sS];

    f32x4 pre[4];   // 16 consecutive floats of one x row in flight (16 VGPRs)

#define ISSUE(t0_)                                                              \
    {                                                                           \
        int rr = (t0_) + sT;                                                    \
        rr = (sln > 0) ? (rr < sln ? rr : sln - 1) : 0;                         \
        long long row = (long long)sst + rr;                                    \
        row = row < (long long)(N - 1) ? row : (long long)(N - 1);              \
        const f32x4* p_ = (const f32x4*)(x + row * HDIM + sC * 16);             \
        pre[0] = p_[0]; pre[1] = p_[1]; pre[2] = p_[2]; pre[3] = p_[3];         \
    }
#define COMMIT()                                                                \
    {                                                                           \
        uint4 o1, o2;                                                           \
        o1.x = pk2(pre[0][0], pre[0][1]); o1.y = pk2(pre[0][2], pre[0][3]);     \
        o1.z = pk2(pre[1][0], pre[1][1]); o1.w = pk2(pre[1][2], pre[1][3]);     \
        o2.x = pk2(pre[2][0], pre[2][1]); o2.y = pk2(pre[2][2], pre[2][3]);     \
        o2.z = pk2(pre[3][0], pre[3][1]); o2.w = pk2(pre[3][2], pre[3][3]);     \
        unsigned short* d_ = &xst[sS * SPLANE + sT * SROW + sC * 16];           \
        *(uint4*)d_ = o1; *(uint4*)(d_ + 8) = o2;                               \
    }

    // x A-frag source plane for this lane's A-row (l15): real seg or zero plane.
    const int xp = (l15 & 2) ? 8 : ((l15 >> 2) * 2 + (l15 & 1));
    const unsigned short* xb = &xst[xp * SPLANE + quad * 8];

    float c2[2] = {0, 0}, h2[2] = {0, 0};
    const f32x4 cz = {0.0f, 0.0f, 0.0f, 0.0f};
    const int nch = (lmax + CH - 1) / CH;

    if (nch > 0) {
        ISSUE(0);
        COMMIT();
        __syncthreads();
        ISSUE(CH);

        for (int ch = 0; ch < nch; ++ch) {
            const int t0 = ch * CH;
#pragma unroll
            for (int tt = 0; tt < CH; ++tt) {
                const int t = t0 + tt;          // t & 1 == tt & 1 (CH even)
                const int pb = tt & 1, nb = pb ^ 1;

                const unsigned short* xr = xb + tt * SROW;
                bf16x8 xa0 = *(const bf16x8*)(xr);
                bf16x8 xa1 = *(const bf16x8*)(xr + 32);
                const unsigned short* hr = &hst[pb][l15][quad * 8];
                bf16x8 ha0 = *(const bf16x8*)(hr);
                bf16x8 ha1 = *(const bf16x8*)(hr + 32);

                f32x4 acc[4];
#pragma unroll
                for (int g = 0; g < 4; ++g) {
                    f32x4 a = __builtin_amdgcn_mfma_f32_16x16x32_bf16(xa0, wi[g][0], cz, 0, 0, 0);
                    a = __builtin_amdgcn_mfma_f32_16x16x32_bf16(xa1, wi[g][1], a, 0, 0, 0);
                    a = __builtin_amdgcn_mfma_f32_16x16x32_bf16(ha0, wh[g][0], a, 0, 0, 0);
                    a = __builtin_amdgcn_mfma_f32_16x16x32_bf16(ha1, wh[g][1], a, 0, 0, 0);
                    acc[g] = a;
                }

                // Gate math: 2 real bundles per lane (C regs 0..1 = segs 2q, 2q+1).
#pragma unroll
                for (int r = 0; r < 2; ++r) {
                    float gi = sig_b (acc[0][r], bs[0]);
                    float gf = sig_b (acc[1][r], bs[1]);
                    float gg = tanh_b(acc[2][r], bs[2]);
                    float go = sig_b (acc[3][r], bs[3]);
                    float cn = fmaf(gf, c2[r], gi * gg);
                    float hn = go * tanh_p(cn);
                    const bool up = t < len2[r];
                    c2[r] = up ? cn : c2[r];
                    h2[r] = up ? hn : h2[r];
                    hst[nb][quad * 4 + r][ncol] = f2bf_u(h2[r]);
                }
                __syncthreads();
            }
            if (ch + 1 < nch) {
                COMMIT();
                __syncthreads();
                ISSUE((ch + 2) * CH);
            }
        }
    }

#pragma unroll
    for (int r = 0; r < 2; ++r) {
        const int seg = segbase + 2 * quad + r;
        if (seg < B) out[(size_t)seg * HDIM + ncol] = h2[r];
    }
#undef ISSUE
#undef COMMIT
}

extern "C" void kernel_launch(void* const* d_in, const int* in_sizes, int n_in,
                              void* d_out, int out_size, void* d_ws, size_t ws_size,
                              hipStream_t stream) {
    const float* x     = (const float*)d_in[0];
    const float* Wih   = (const float*)d_in[1];
    const float* Whh   = (const float*)d_in[2];
    const float* bih   = (const float*)d_in[3];
    const float* bhh   = (const float*)d_in[4];
    const int*   index = (const int*)d_in[5];

    const int N = in_sizes[5];
    const int B = out_size / HDIM;   // 8192

    const int nblocks = (B + 7) / 8;   // 1024 -> 4 blocks/CU, one generation
    lstm8_kernel<<<nblocks, 256, 0, stream>>>(x, Wih, Whh, bih, bhh, index,
                                              (float*)d_out, N, B);
}